// Round 2
// baseline (400.002 us; speedup 1.0000x reference)
//
#include <hip/hip_runtime.h>
#include <math.h>

// Problem constants
// O=64, I=64, K=3, NH=64, M=32, TEMP=0.5, F_GAMMA=0.3, PAD=1, B=64, T=8192
#define TT 128
#define TP 72   // xs[t][i] row pitch in bf16: 144 B = 9*16 -> every row b128-aligned

typedef short bf16x8 __attribute__((ext_vector_type(8)));
typedef float f32x4 __attribute__((ext_vector_type(4)));
typedef unsigned short u16x4 __attribute__((ext_vector_type(4)));

__device__ __forceinline__ unsigned short f2bf(float f) {
  union { float f; unsigned int u; } v; v.f = f;
  unsigned int u = v.u;
  u += 0x7fffu + ((u >> 16) & 1u);   // round-to-nearest-even
  return (unsigned short)(u >> 16);
}

// ---------------- kernel 1: fused rep + q pipeline -> scw (bf16 [k][o][i]) + sbias ----------------
// 512 threads, 1 block. rep computed into LDS (replaces the old k_rep kernel).
__global__ void k_qpipe(const float* __restrict__ grads, const float* __restrict__ ctrl_w,
    const float* __restrict__ ctrl_b, const float* __restrict__ q_ema,
    const float* __restrict__ W, const float* __restrict__ conv_w, const float* __restrict__ conv_b,
    const float* __restrict__ cw_w, const float* __restrict__ cw_b,
    const float* __restrict__ cb_w, const float* __restrict__ cb_b,
    const float* __restrict__ cf_w, const float* __restrict__ cf_b,
    const float* __restrict__ tau_w1, const float* __restrict__ tau_b1,
    const float* __restrict__ tau_w2, const float* __restrict__ tau_b2,
    const int* __restrict__ trigger,
    unsigned short* __restrict__ scw, float* __restrict__ sbias) {
  __shared__ float s_rep[4096];   // rep (64x64) lives in LDS now
  __shared__ float s_q1[320];
  __shared__ float s_q2[320];
  __shared__ float s_h[64 * 17];
  __shared__ float s_s[64];
  __shared__ float s_part[320];
  __shared__ float s_att[32];
  __shared__ float s_red[4];   // tau, v0, v1, v2
  __shared__ int   s_idx[3];
  int tid = threadIdx.x;       // 0..511

  // ---- rep = silu(g @ ctrl_w^T + ctrl_b), (64x64) ----
  for (int e = tid; e < 4096; e += 512) {
    int r = e >> 6, c = e & 63;
    const float4* g4 = (const float4*)(grads + r * 192);
    const float4* w4 = (const float4*)(ctrl_w + c * 192);
    float acc = ctrl_b[c];
    #pragma unroll 8
    for (int j = 0; j < 48; ++j) {
      float4 a = g4[j], b = w4[j];
      acc += a.x * b.x + a.y * b.y + a.z * b.z + a.w * b.w;
    }
    float sg = 1.0f / (1.0f + expf(-acc));
    s_rep[e] = acc * sg;
  }
  __syncthreads();

  // ---- q0 (w|b|f) -> q1 = 0.85*q0 + 0.15*q_ema ----
  if (tid < 320) {
    const float* wrow; float bias; int r;
    if (tid < 192)      { r = tid / 3; int k = tid - r * 3; wrow = cw_w + k * 64; bias = cw_b[k]; }
    else if (tid < 256) { r = tid - 192; wrow = cb_w; bias = cb_b[0]; }
    else                { r = tid - 256; wrow = cf_w; bias = cf_b[0]; }
    float acc = bias;
    const float4* rp = (const float4*)(s_rep + r * 64);
    const float4* wp = (const float4*)wrow;
    #pragma unroll
    for (int j = 0; j < 16; ++j) {
      float4 a = rp[j], b = wp[j];
      acc += a.x * b.x + a.y * b.y + a.z * b.z + a.w * b.w;
    }
    s_q1[tid] = 0.85f * acc + 0.15f * q_ema[tid];
  }
  // ---- h = silu(rep @ tau_w1^T + tau_b1), (64x16) ----
  for (int e = tid; e < 1024; e += 512) {
    int r = e >> 4, u = e & 15;
    float acc = tau_b1[u];
    const float4* rp = (const float4*)(s_rep + r * 64);
    const float4* wp = (const float4*)(tau_w1 + u * 64);
    #pragma unroll
    for (int j = 0; j < 16; ++j) {
      float4 a = rp[j], b = wp[j];
      acc += a.x * b.x + a.y * b.y + a.z * b.z + a.w * b.w;
    }
    s_h[r * 17 + u] = acc / (1.0f + expf(-acc));
  }
  __syncthreads();
  // ---- s[r] = sigmoid(h @ tau_w2^T + tau_b2) ----
  if (tid < 64) {
    float acc = tau_b2[0];
    #pragma unroll
    for (int u = 0; u < 16; ++u) acc += s_h[tid * 17 + u] * tau_w2[u];
    s_s[tid] = 1.0f / (1.0f + expf(-acc));
  }
  // ---- att logits partials: q1 @ W / TEMP ----
  if (tid < 320) {
    int m = tid & 31, pg = tid >> 5;   // pg in 0..9
    float acc = 0.f;
    #pragma unroll
    for (int pp = 0; pp < 32; ++pp) {
      int p = pg * 32 + pp;
      acc += s_q1[p] * W[p * 32 + m];
    }
    s_part[tid] = acc;
  }
  __syncthreads();
  if (tid < 32) {
    float acc = 0.f;
    #pragma unroll
    for (int pg = 0; pg < 10; ++pg) acc += s_part[pg * 32 + tid];
    s_att[tid] = acc * 2.0f;   // /TEMP, TEMP=0.5
  }
  __syncthreads();
  // ---- tau, softmax, top-3 (single thread; 32 values) ----
  if (tid == 0) {
    float tau = 0.f;
    for (int r = 0; r < 64; ++r) tau += s_s[r];
    tau = tau * (1.0f / 64.0f) * 0.5f + 0.5f;
    float mx = s_att[0];
    for (int m = 1; m < 32; ++m) mx = fmaxf(mx, s_att[m]);
    float pr[32]; float sum = 0.f;
    #pragma unroll
    for (int m = 0; m < 32; ++m) { pr[m] = expf(s_att[m] - mx); sum += pr[m]; }
    float inv = 1.0f / sum;
    int i0 = -1, i1 = -1, i2 = -1; float v0 = -1.f, v1 = -1.f, v2 = -1.f;
    #pragma unroll
    for (int m = 0; m < 32; ++m) {
      float v = pr[m];
      if (v > v0)      { v2 = v1; i2 = i1; v1 = v0; i1 = i0; v0 = v; i0 = m; }
      else if (v > v1) { v2 = v1; i2 = i1; v1 = v; i1 = m; }
      else if (v > v2) { v2 = v; i2 = m; }
    }
    s_red[0] = tau; s_red[1] = v0 * inv; s_red[2] = v1 * inv; s_red[3] = v2 * inv;
    s_idx[0] = i0; s_idx[1] = i1; s_idx[2] = i2;
  }
  __syncthreads();
  // ---- q2 = tau*q1 + (1-tau)*old_q (if trigger) ----
  if (tid < 320) {
    float q1 = s_q1[tid];
    float q2;
    if (trigger[0] == 1) {
      float tau = s_red[0];
      float oq = W[tid * 32 + s_idx[0]] * s_red[1]
               + W[tid * 32 + s_idx[1]] * s_red[2]
               + W[tid * 32 + s_idx[2]] * s_red[3];
      q2 = tau * q1 + (1.0f - tau) * oq;
    } else {
      q2 = q1;
    }
    s_q2[tid] = q2;
  }
  __syncthreads();
  // ---- scw[k][o][i] = conv_w[o][i][k] * wq[o][k] * fq[o]  (bf16) ----
  for (int e = tid; e < 12288; e += 512) {
    int k = e >> 12, rem = e & 4095;
    int o = rem >> 6, i = rem & 63;
    float val = conv_w[(o * 64 + i) * 3 + k] * s_q2[o * 3 + k] * s_q2[256 + o];
    scw[e] = f2bf(val);
  }
  // ---- sbias[o] = fq*conv_b*bq ----
  if (tid < 64) sbias[tid] = s_q2[256 + tid] * conv_b[tid] * s_q2[192 + tid];
}

// ---------------- kernel 2: conv as bf16 MFMA GEMM, swapped operands ----------------
// D[t][o] = sum_i x[t+k-1][i] * w_k[o][i].  A-operand = x (M dim = t), B = weights
// (N dim = o).  C/D: row = t = quad*4+reg, col = o = lane&15 -> each lane holds 4
// consecutive t at one o => float4 output stores, fully coalesced.
// Block: 256 threads / 4 waves; tile 128 t x 64 o; wave = 64 t x 32 o.
// Staging: 8 float4 global loads/thread (one vmcnt window), transpose via 4x
// ds_write_b16 each into xs[t][i] (TP=72 keeps rows b128-aligned).
__global__ __launch_bounds__(256, 4) void k_conv(const float* __restrict__ x,
    const unsigned short* __restrict__ scw, const float* __restrict__ sbias,
    float* __restrict__ out) {
  __shared__ __align__(16) unsigned short xs[130 * TP];   // [tr][i], tr = t_local + 1
  __shared__ float sb[64];
  const int tid = threadIdx.x;
  const int b = blockIdx.y;
  const int t0 = blockIdx.x * TT;

  const int lane = tid & 63;
  const int wv   = tid >> 6;
  const int quad = lane >> 4;
  const int l15  = lane & 15;
  const int wt   = (wv & 1) * 64;   // wave t-offset within tile
  const int wo   = (wv >> 1) * 32;  // wave o-offset

  if (tid < 64) sb[tid] = sbias[tid];

  // B fragments (weights): B[c = quad*8+j][n = l15], n->o, c->i. 12 x 16B loads (L2-hot).
  bf16x8 wfr[3][2][2];
  #pragma unroll
  for (int k = 0; k < 3; ++k)
    #pragma unroll
    for (int ii = 0; ii < 2; ++ii)
      #pragma unroll
      for (int n = 0; n < 2; ++n)
        wfr[k][ii][n] = *(const bf16x8*)(scw + k * 4096 + (wo + n * 16 + l15) * 64 + ii * 32 + quad * 8);

  // ---- stage x[b, :, t0-1 .. t0+128] transposed into xs[t][i] ----
  // Interior: lane-major along t: lanes 0..31 read 32 consecutive float4 of one
  // i-row. 8 independent loads issued in one batch -> single HBM round trip.
  const int tl4 = tid & 31;    // float4-column within row (t = tl4*4 .. +3)
  const int ib  = tid >> 5;    // base i row (0..7)
  const float* xb = x + (size_t)b * (64 * 8192);
  const float* xp = xb + (size_t)ib * 8192 + t0 + tl4 * 4;
  float4 arr[8];
  #pragma unroll
  for (int it = 0; it < 8; ++it)
    arr[it] = *(const float4*)(xp + (size_t)it * 8 * 8192);

  // Halo loads (t0-1, t0+128) issued in the same vmcnt window.
  float hv = 0.0f;
  if (tid < 128) {
    const int side = tid >> 6;
    const int i    = tid & 63;
    const int tg   = side ? (t0 + TT) : (t0 - 1);
    if (tg >= 0 && tg < 8192) hv = xb[(size_t)i * 8192 + tg];
  }

  // Transpose-convert interior: 4 scalar b16 writes per float4.
  #pragma unroll
  for (int it = 0; it < 8; ++it) {
    const int i = ib + it * 8;
    unsigned short* p = xs + (tl4 * 4 + 1) * TP + i;
    p[0 * TP] = f2bf(arr[it].x);
    p[1 * TP] = f2bf(arr[it].y);
    p[2 * TP] = f2bf(arr[it].z);
    p[3 * TP] = f2bf(arr[it].w);
  }
  if (tid < 128) {
    const int side = tid >> 6;
    const int i    = tid & 63;
    xs[(side ? 129 : 0) * TP + i] = f2bf(hv);
  }

  __syncthreads();

  f32x4 acc[4][2];   // [m (t-frag)][n (o-frag)]
  #pragma unroll
  for (int m = 0; m < 4; ++m)
    #pragma unroll
    for (int n = 0; n < 2; ++n)
      acc[m][n] = (f32x4){0.f, 0.f, 0.f, 0.f};

  // A fragment (x): A[m = l15][c = quad*8+j]: row tr = wt + m*16 + l15 + k,
  // cols i = ii*32 + quad*8 .. +7 -> one ds_read_b128, compile-time offsets.
  const char* xsb = (const char*)xs + (wt + l15) * (TP * 2) + quad * 16;
  #pragma unroll
  for (int k = 0; k < 3; ++k) {
    #pragma unroll
    for (int ii = 0; ii < 2; ++ii) {
      #pragma unroll
      for (int m = 0; m < 4; ++m) {
        const bf16x8 afr = *(const bf16x8*)(xsb + (m * 16 + k) * (TP * 2) + ii * 64);
        acc[m][0] = __builtin_amdgcn_mfma_f32_16x16x32_bf16(afr, wfr[k][ii][0], acc[m][0], 0, 0, 0);
        acc[m][1] = __builtin_amdgcn_mfma_f32_16x16x32_bf16(afr, wfr[k][ii][1], acc[m][1], 0, 0, 0);
      }
    }
  }

  // epilogue: lane holds t = quad*4 + {0..3} at o = wo + n*16 + l15 -> float4 store.
  #pragma unroll
  for (int m = 0; m < 4; ++m) {
    #pragma unroll
    for (int n = 0; n < 2; ++n) {
      const int o = wo + n * 16 + l15;
      const float bias = sb[o];
      f32x4 v = acc[m][n];
      v[0] += bias; v[1] += bias; v[2] += bias; v[3] += bias;
      float* op = out + ((size_t)(b * 64 + o)) * 8192 + t0 + wt + m * 16 + quad * 4;
      *(f32x4*)op = v;
    }
  }
}

extern "C" void kernel_launch(void* const* d_in, const int* in_sizes, int n_in,
                              void* d_out, int out_size, void* d_ws, size_t ws_size,
                              hipStream_t stream) {
  const float* x      = (const float*)d_in[0];
  const float* grads  = (const float*)d_in[1];
  const float* q_ema  = (const float*)d_in[2];
  const float* W      = (const float*)d_in[3];
  const float* conv_w = (const float*)d_in[4];
  const float* conv_b = (const float*)d_in[5];
  const float* ctrl_w = (const float*)d_in[6];
  const float* ctrl_b = (const float*)d_in[7];
  const float* cw_w   = (const float*)d_in[8];
  const float* cw_b   = (const float*)d_in[9];
  const float* cb_w   = (const float*)d_in[10];
  const float* cb_b   = (const float*)d_in[11];
  const float* cf_w   = (const float*)d_in[12];
  const float* cf_b   = (const float*)d_in[13];
  const float* tau_w1 = (const float*)d_in[14];
  const float* tau_b1 = (const float*)d_in[15];
  const float* tau_w2 = (const float*)d_in[16];
  const float* tau_b2 = (const float*)d_in[17];
  const int*   trigger = (const int*)d_in[18];
  float* out = (float*)d_out;

  // workspace layout: scw bf16[12288] @16384 | sbias fp32[64] @40960
  unsigned short* ws_scw   = (unsigned short*)((char*)d_ws + 16384);
  float*          ws_sbias = (float*)((char*)d_ws + 16384 + 24576);

  k_qpipe<<<1, 512, 0, stream>>>(grads, ctrl_w, ctrl_b, q_ema, W, conv_w, conv_b,
                                 cw_w, cw_b, cb_w, cb_b, cf_w, cf_b,
                                 tau_w1, tau_b1, tau_w2, tau_b2, trigger,
                                 ws_scw, ws_sbias);
  k_conv<<<dim3(64, 64), 256, 0, stream>>>(x, ws_scw, ws_sbias, out);
}

// Round 3
// 335.250 us; speedup vs baseline: 1.1931x; 1.1931x over previous
//
#include <hip/hip_runtime.h>
#include <math.h>

// Problem constants
// O=64, I=64, K=3, NH=64, M=32, TEMP=0.5, F_GAMMA=0.3, PAD=1, B=64, T=8192
#define TT 128
#define TP 72   // xs[t][i] row pitch in bf16: 144 B = 9*16 -> every row b128-aligned
#define NT 8    // t-tiles per block (persistent along t, double-buffered LDS)

typedef short bf16x8 __attribute__((ext_vector_type(8)));
typedef float f32x4 __attribute__((ext_vector_type(4)));
typedef unsigned short u16x4 __attribute__((ext_vector_type(4)));

__device__ __forceinline__ unsigned short f2bf(float f) {
  union { float f; unsigned int u; } v; v.f = f;
  unsigned int u = v.u;
  u += 0x7fffu + ((u >> 16) & 1u);   // round-to-nearest-even
  return (unsigned short)(u >> 16);
}

// ---------------- kernel 1a: rep = silu(g @ ctrl_w^T + ctrl_b), (64x64) ----------------
// 16 blocks x 256 threads: spread across CUs (single-block fusion was a 135us regression).
__global__ void k_rep(const float* __restrict__ grads, const float* __restrict__ ctrl_w,
                      const float* __restrict__ ctrl_b, float* __restrict__ rep_out) {
  int idx = blockIdx.x * 256 + threadIdx.x;   // 0..4095
  int r = idx >> 6, c = idx & 63;
  const float4* g4 = (const float4*)(grads + r * 192);
  const float4* w4 = (const float4*)(ctrl_w + c * 192);
  float acc = ctrl_b[c];
  #pragma unroll 8
  for (int j = 0; j < 48; ++j) {
    float4 a = g4[j], b = w4[j];
    acc += a.x * b.x + a.y * b.y + a.z * b.z + a.w * b.w;
  }
  float sg = 1.0f / (1.0f + expf(-acc));
  rep_out[idx] = acc * sg;   // silu
}

// ---------------- kernel 1b: full q pipeline -> scw (bf16 [k][o][i]) + sbias ----------------
__global__ void k_qpipe(const float* __restrict__ rep, const float* __restrict__ q_ema,
    const float* __restrict__ W, const float* __restrict__ conv_w, const float* __restrict__ conv_b,
    const float* __restrict__ cw_w, const float* __restrict__ cw_b,
    const float* __restrict__ cb_w, const float* __restrict__ cb_b,
    const float* __restrict__ cf_w, const float* __restrict__ cf_b,
    const float* __restrict__ tau_w1, const float* __restrict__ tau_b1,
    const float* __restrict__ tau_w2, const float* __restrict__ tau_b2,
    const int* __restrict__ trigger,
    unsigned short* __restrict__ scw, float* __restrict__ sbias) {
  __shared__ float s_q1[320];
  __shared__ float s_q2[320];
  __shared__ float s_h[64 * 17];
  __shared__ float s_s[64];
  __shared__ float s_part[320];
  __shared__ float s_att[32];
  __shared__ float s_red[4];   // tau, v0, v1, v2
  __shared__ int   s_idx[3];
  int tid = threadIdx.x;       // 0..319

  // ---- q0 (w|b|f) -> q1 = 0.85*q0 + 0.15*q_ema ----
  {
    const float* wrow; float bias; int r;
    if (tid < 192)      { r = tid / 3; int k = tid - r * 3; wrow = cw_w + k * 64; bias = cw_b[k]; }
    else if (tid < 256) { r = tid - 192; wrow = cb_w; bias = cb_b[0]; }
    else                { r = tid - 256; wrow = cf_w; bias = cf_b[0]; }
    float acc = bias;
    const float4* rp = (const float4*)(rep + r * 64);
    const float4* wp = (const float4*)wrow;
    #pragma unroll
    for (int j = 0; j < 16; ++j) {
      float4 a = rp[j], b = wp[j];
      acc += a.x * b.x + a.y * b.y + a.z * b.z + a.w * b.w;
    }
    s_q1[tid] = 0.85f * acc + 0.15f * q_ema[tid];
  }
  // ---- h = silu(rep @ tau_w1^T + tau_b1), (64x16) ----
  for (int e = tid; e < 1024; e += 320) {
    int r = e >> 4, u = e & 15;
    float acc = tau_b1[u];
    const float4* rp = (const float4*)(rep + r * 64);
    const float4* wp = (const float4*)(tau_w1 + u * 64);
    #pragma unroll
    for (int j = 0; j < 16; ++j) {
      float4 a = rp[j], b = wp[j];
      acc += a.x * b.x + a.y * b.y + a.z * b.z + a.w * b.w;
    }
    s_h[r * 17 + u] = acc / (1.0f + expf(-acc));
  }
  __syncthreads();
  // ---- s[r] = sigmoid(h @ tau_w2^T + tau_b2) ----
  if (tid < 64) {
    float acc = tau_b2[0];
    #pragma unroll
    for (int u = 0; u < 16; ++u) acc += s_h[tid * 17 + u] * tau_w2[u];
    s_s[tid] = 1.0f / (1.0f + expf(-acc));
  }
  // ---- att logits partials: q1 @ W / TEMP ----
  {
    int m = tid & 31, pg = tid >> 5;   // pg in 0..9
    float acc = 0.f;
    #pragma unroll
    for (int pp = 0; pp < 32; ++pp) {
      int p = pg * 32 + pp;
      acc += s_q1[p] * W[p * 32 + m];
    }
    s_part[tid] = acc;
  }
  __syncthreads();
  if (tid < 32) {
    float acc = 0.f;
    #pragma unroll
    for (int pg = 0; pg < 10; ++pg) acc += s_part[pg * 32 + tid];
    s_att[tid] = acc * 2.0f;   // /TEMP, TEMP=0.5
  }
  __syncthreads();
  // ---- tau, softmax, top-3 (single thread; 32 values) ----
  if (tid == 0) {
    float tau = 0.f;
    for (int r = 0; r < 64; ++r) tau += s_s[r];
    tau = tau * (1.0f / 64.0f) * 0.5f + 0.5f;
    float mx = s_att[0];
    for (int m = 1; m < 32; ++m) mx = fmaxf(mx, s_att[m]);
    float pr[32]; float sum = 0.f;
    #pragma unroll
    for (int m = 0; m < 32; ++m) { pr[m] = expf(s_att[m] - mx); sum += pr[m]; }
    float inv = 1.0f / sum;
    int i0 = -1, i1 = -1, i2 = -1; float v0 = -1.f, v1 = -1.f, v2 = -1.f;
    #pragma unroll
    for (int m = 0; m < 32; ++m) {
      float v = pr[m];
      if (v > v0)      { v2 = v1; i2 = i1; v1 = v0; i1 = i0; v0 = v; i0 = m; }
      else if (v > v1) { v2 = v1; i2 = i1; v1 = v; i1 = m; }
      else if (v > v2) { v2 = v; i2 = m; }
    }
    s_red[0] = tau; s_red[1] = v0 * inv; s_red[2] = v1 * inv; s_red[3] = v2 * inv;
    s_idx[0] = i0; s_idx[1] = i1; s_idx[2] = i2;
  }
  __syncthreads();
  // ---- q2 = tau*q1 + (1-tau)*old_q (if trigger) ----
  {
    float q1 = s_q1[tid];
    float q2;
    if (trigger[0] == 1) {
      float tau = s_red[0];
      float oq = W[tid * 32 + s_idx[0]] * s_red[1]
               + W[tid * 32 + s_idx[1]] * s_red[2]
               + W[tid * 32 + s_idx[2]] * s_red[3];
      q2 = tau * q1 + (1.0f - tau) * oq;
    } else {
      q2 = q1;
    }
    s_q2[tid] = q2;
  }
  __syncthreads();
  // ---- scw[k][o][i] = conv_w[o][i][k] * wq[o][k] * fq[o]  (bf16) ----
  for (int e = tid; e < 12288; e += 320) {
    int k = e >> 12, rem = e & 4095;
    int o = rem >> 6, i = rem & 63;
    float val = conv_w[(o * 64 + i) * 3 + k] * s_q2[o * 3 + k] * s_q2[256 + o];
    scw[e] = f2bf(val);
  }
  // ---- sbias[o] = fq*conv_b*bq ----
  if (tid < 64) sbias[tid] = s_q2[256 + tid] * conv_b[tid] * s_q2[192 + tid];
}

// ---------------- kernel 2: conv as bf16 MFMA GEMM, pipelined multi-tile ----------------
// D[t][o] = sum_i x[t+k-1][i] * w_k[o][i].  A = x (M=t), B = weights (N=o).
// C/D: row=t=quad*4+reg, col=o=lane&15 -> float4 output stores.
// Each block walks NT=8 consecutive t-tiles (128 t each) with double-buffered LDS:
//   iter j: sync; issue global loads for tile j+1; compute tile j (ds_read_b128 +
//   MFMA + float4 stores); convert+ds_write tile j+1 into the alternate buffer.
// HBM latency of tile j+1 hides under tile j's compute.  Grid (8,64) = 512 blocks
// = exactly 2 resident blocks/CU (no tail); launch_bounds(256,2) keeps all 8
// staged float4 live across the compute phase (no forced 64-VGPR packing).
__global__ __launch_bounds__(256, 2) void k_conv(const float* __restrict__ x,
    const unsigned short* __restrict__ scw, const float* __restrict__ sbias,
    float* __restrict__ out) {
  __shared__ __align__(16) unsigned short xs[2][130 * TP];   // [buf][tr*TP + i], tr = t_local + 1
  __shared__ float sb[64];
  const int tid = threadIdx.x;
  const int b = blockIdx.y;
  const int tile0 = blockIdx.x * NT;   // tile index; t0 = (tile0+j)*TT

  const int lane = tid & 63;
  const int wv   = tid >> 6;
  const int quad = lane >> 4;
  const int l15  = lane & 15;
  const int wt   = (wv & 1) * 64;   // wave t-offset within tile
  const int wo   = (wv >> 1) * 32;  // wave o-offset

  if (tid < 64) sb[tid] = sbias[tid];

  // B fragments (weights): B[c = quad*8+j][n = l15], n->o, c->i. 12 x 16B loads (L2-hot).
  bf16x8 wfr[3][2][2];
  #pragma unroll
  for (int k = 0; k < 3; ++k)
    #pragma unroll
    for (int ii = 0; ii < 2; ++ii)
      #pragma unroll
      for (int n = 0; n < 2; ++n)
        wfr[k][ii][n] = *(const bf16x8*)(scw + k * 4096 + (wo + n * 16 + l15) * 64 + ii * 32 + quad * 8);

  const float* xb = x + (size_t)b * (64 * 8192);
  const int tl4 = tid & 31;    // float4-column within row (t = tl4*4 .. +3)
  const int ib  = tid >> 5;    // base i row (0..7)
  const int hside = tid >> 6;  // halo side (valid for tid<128)
  const int hi    = tid & 63;  // halo i row

  float4 arr[8];
  float hv = 0.0f;

  // Issue interior (8x float4, coalesced: 32 lanes x 16B = 512B/instr) + halo
  // loads for a tile; results land in regs, vmcnt waited only at write_tile.
  auto load_tile = [&](int t0) {
    const float* xp = xb + (size_t)ib * 8192 + t0 + tl4 * 4;
    #pragma unroll
    for (int it = 0; it < 8; ++it)
      arr[it] = *(const float4*)(xp + (size_t)it * 8 * 8192);
    hv = 0.0f;
    if (tid < 128) {
      const int tg = hside ? (t0 + TT) : (t0 - 1);
      if (tg >= 0 && tg < 8192) hv = xb[(size_t)hi * 8192 + tg];
    }
  };
  // Convert fp32->bf16 and transpose into xs[t][i].
  auto write_tile = [&](unsigned short* bufp) {
    #pragma unroll
    for (int it = 0; it < 8; ++it) {
      const int i = ib + it * 8;
      unsigned short* p = bufp + (tl4 * 4 + 1) * TP + i;
      p[0 * TP] = f2bf(arr[it].x);
      p[1 * TP] = f2bf(arr[it].y);
      p[2 * TP] = f2bf(arr[it].z);
      p[3 * TP] = f2bf(arr[it].w);
    }
    if (tid < 128) bufp[(hside ? 129 : 0) * TP + hi] = f2bf(hv);
  };

  // prologue: stage tile 0
  load_tile(tile0 * TT);
  write_tile(xs[0]);

  for (int j = 0; j < NT; ++j) {
    __syncthreads();   // buf[j&1] fully written; also orders ds_writes vs prior readers

    if (j < NT - 1) load_tile((tile0 + j + 1) * TT);   // overlap HBM with compute below

    const unsigned short* cur = xs[j & 1];
    f32x4 acc[4][2];   // [m (t-frag)][n (o-frag)]
    #pragma unroll
    for (int m = 0; m < 4; ++m)
      #pragma unroll
      for (int n = 0; n < 2; ++n)
        acc[m][n] = (f32x4){0.f, 0.f, 0.f, 0.f};

    // A fragment (x): row tr = wt + m*16 + l15 + k, cols i = ii*32+quad*8 .. +7
    //   -> one ds_read_b128 each, compile-time offsets off a per-thread base.
    const char* xsb = (const char*)cur + (wt + l15) * (TP * 2) + quad * 16;
    #pragma unroll
    for (int k = 0; k < 3; ++k) {
      #pragma unroll
      for (int ii = 0; ii < 2; ++ii) {
        #pragma unroll
        for (int m = 0; m < 4; ++m) {
          const bf16x8 afr = *(const bf16x8*)(xsb + (m * 16 + k) * (TP * 2) + ii * 64);
          acc[m][0] = __builtin_amdgcn_mfma_f32_16x16x32_bf16(afr, wfr[k][ii][0], acc[m][0], 0, 0, 0);
          acc[m][1] = __builtin_amdgcn_mfma_f32_16x16x32_bf16(afr, wfr[k][ii][1], acc[m][1], 0, 0, 0);
        }
      }
    }

    // epilogue: lane holds t = quad*4 + {0..3} at o = wo + n*16 + l15 -> float4 store.
    const int t0 = (tile0 + j) * TT;
    #pragma unroll
    for (int m = 0; m < 4; ++m) {
      #pragma unroll
      for (int n = 0; n < 2; ++n) {
        const int o = wo + n * 16 + l15;
        const float bias = sb[o];
        f32x4 v = acc[m][n];
        v[0] += bias; v[1] += bias; v[2] += bias; v[3] += bias;
        float* op = out + ((size_t)(b * 64 + o)) * 8192 + t0 + wt + m * 16 + quad * 4;
        *(f32x4*)op = v;
      }
    }

    if (j < NT - 1) write_tile(&xs[(j + 1) & 1][0]);   // vmcnt drain happens here
  }
}

extern "C" void kernel_launch(void* const* d_in, const int* in_sizes, int n_in,
                              void* d_out, int out_size, void* d_ws, size_t ws_size,
                              hipStream_t stream) {
  const float* x      = (const float*)d_in[0];
  const float* grads  = (const float*)d_in[1];
  const float* q_ema  = (const float*)d_in[2];
  const float* W      = (const float*)d_in[3];
  const float* conv_w = (const float*)d_in[4];
  const float* conv_b = (const float*)d_in[5];
  const float* ctrl_w = (const float*)d_in[6];
  const float* ctrl_b = (const float*)d_in[7];
  const float* cw_w   = (const float*)d_in[8];
  const float* cw_b   = (const float*)d_in[9];
  const float* cb_w   = (const float*)d_in[10];
  const float* cb_b   = (const float*)d_in[11];
  const float* cf_w   = (const float*)d_in[12];
  const float* cf_b   = (const float*)d_in[13];
  const float* tau_w1 = (const float*)d_in[14];
  const float* tau_b1 = (const float*)d_in[15];
  const float* tau_w2 = (const float*)d_in[16];
  const float* tau_b2 = (const float*)d_in[17];
  const int*   trigger = (const int*)d_in[18];
  float* out = (float*)d_out;

  // workspace layout: rep fp32[4096] @0 | scw bf16[12288] @16384 | sbias fp32[64] @40960
  float*          ws_rep   = (float*)d_ws;
  unsigned short* ws_scw   = (unsigned short*)((char*)d_ws + 16384);
  float*          ws_sbias = (float*)((char*)d_ws + 16384 + 24576);

  k_rep<<<16, 256, 0, stream>>>(grads, ctrl_w, ctrl_b, ws_rep);
  k_qpipe<<<1, 320, 0, stream>>>(ws_rep, q_ema, W, conv_w, conv_b, cw_w, cw_b, cb_w, cb_b,
                                 cf_w, cf_b, tau_w1, tau_b1, tau_w2, tau_b2, trigger,
                                 ws_scw, ws_sbias);
  k_conv<<<dim3(8, 64), 256, 0, stream>>>(x, ws_scw, ws_sbias, out);
}

// Round 4
// 302.910 us; speedup vs baseline: 1.3205x; 1.1068x over previous
//
#include <hip/hip_runtime.h>
#include <math.h>

// Problem constants
// O=64, I=64, K=3, NH=64, M=32, TEMP=0.5, F_GAMMA=0.3, PAD=1, B=64, T=8192
#define TT 128
#define TP 72   // xs[t][i] row pitch in bf16: 144 B = 9*16 -> every row b128-aligned,
                // and 36-dword row stride spreads stride-4-row writes across banks.

typedef short bf16x8 __attribute__((ext_vector_type(8)));
typedef float f32x4 __attribute__((ext_vector_type(4)));
typedef unsigned short u16x8 __attribute__((ext_vector_type(8)));

__device__ __forceinline__ unsigned short f2bf(float f) {
  union { float f; unsigned int u; } v; v.f = f;
  unsigned int u = v.u;
  u += 0x7fffu + ((u >> 16) & 1u);   // round-to-nearest-even
  return (unsigned short)(u >> 16);
}

// ---------------- kernel 1a: rep = silu(g @ ctrl_w^T + ctrl_b), (64x64) ----------------
// 16 blocks x 256 threads: spread across CUs (single-block fusion was a 135us regression).
__global__ void k_rep(const float* __restrict__ grads, const float* __restrict__ ctrl_w,
                      const float* __restrict__ ctrl_b, float* __restrict__ rep_out) {
  int idx = blockIdx.x * 256 + threadIdx.x;   // 0..4095
  int r = idx >> 6, c = idx & 63;
  const float4* g4 = (const float4*)(grads + r * 192);
  const float4* w4 = (const float4*)(ctrl_w + c * 192);
  float acc = ctrl_b[c];
  #pragma unroll 8
  for (int j = 0; j < 48; ++j) {
    float4 a = g4[j], b = w4[j];
    acc += a.x * b.x + a.y * b.y + a.z * b.z + a.w * b.w;
  }
  float sg = 1.0f / (1.0f + expf(-acc));
  rep_out[idx] = acc * sg;   // silu
}

// ---------------- kernel 1b: full q pipeline -> scw (bf16 [k][o][i]) + sbias ----------------
__global__ void k_qpipe(const float* __restrict__ rep, const float* __restrict__ q_ema,
    const float* __restrict__ W, const float* __restrict__ conv_w, const float* __restrict__ conv_b,
    const float* __restrict__ cw_w, const float* __restrict__ cw_b,
    const float* __restrict__ cb_w, const float* __restrict__ cb_b,
    const float* __restrict__ cf_w, const float* __restrict__ cf_b,
    const float* __restrict__ tau_w1, const float* __restrict__ tau_b1,
    const float* __restrict__ tau_w2, const float* __restrict__ tau_b2,
    const int* __restrict__ trigger,
    unsigned short* __restrict__ scw, float* __restrict__ sbias) {
  __shared__ float s_q1[320];
  __shared__ float s_q2[320];
  __shared__ float s_h[64 * 17];
  __shared__ float s_s[64];
  __shared__ float s_part[320];
  __shared__ float s_att[32];
  __shared__ float s_red[4];   // tau, v0, v1, v2
  __shared__ int   s_idx[3];
  int tid = threadIdx.x;       // 0..319

  // ---- q0 (w|b|f) -> q1 = 0.85*q0 + 0.15*q_ema ----
  {
    const float* wrow; float bias; int r;
    if (tid < 192)      { r = tid / 3; int k = tid - r * 3; wrow = cw_w + k * 64; bias = cw_b[k]; }
    else if (tid < 256) { r = tid - 192; wrow = cb_w; bias = cb_b[0]; }
    else                { r = tid - 256; wrow = cf_w; bias = cf_b[0]; }
    float acc = bias;
    const float4* rp = (const float4*)(rep + r * 64);
    const float4* wp = (const float4*)wrow;
    #pragma unroll
    for (int j = 0; j < 16; ++j) {
      float4 a = rp[j], b = wp[j];
      acc += a.x * b.x + a.y * b.y + a.z * b.z + a.w * b.w;
    }
    s_q1[tid] = 0.85f * acc + 0.15f * q_ema[tid];
  }
  // ---- h = silu(rep @ tau_w1^T + tau_b1), (64x16) ----
  for (int e = tid; e < 1024; e += 320) {
    int r = e >> 4, u = e & 15;
    float acc = tau_b1[u];
    const float4* rp = (const float4*)(rep + r * 64);
    const float4* wp = (const float4*)(tau_w1 + u * 64);
    #pragma unroll
    for (int j = 0; j < 16; ++j) {
      float4 a = rp[j], b = wp[j];
      acc += a.x * b.x + a.y * b.y + a.z * b.z + a.w * b.w;
    }
    s_h[r * 17 + u] = acc / (1.0f + expf(-acc));
  }
  __syncthreads();
  // ---- s[r] = sigmoid(h @ tau_w2^T + tau_b2) ----
  if (tid < 64) {
    float acc = tau_b2[0];
    #pragma unroll
    for (int u = 0; u < 16; ++u) acc += s_h[tid * 17 + u] * tau_w2[u];
    s_s[tid] = 1.0f / (1.0f + expf(-acc));
  }
  // ---- att logits partials: q1 @ W / TEMP ----
  {
    int m = tid & 31, pg = tid >> 5;   // pg in 0..9
    float acc = 0.f;
    #pragma unroll
    for (int pp = 0; pp < 32; ++pp) {
      int p = pg * 32 + pp;
      acc += s_q1[p] * W[p * 32 + m];
    }
    s_part[tid] = acc;
  }
  __syncthreads();
  if (tid < 32) {
    float acc = 0.f;
    #pragma unroll
    for (int pg = 0; pg < 10; ++pg) acc += s_part[pg * 32 + tid];
    s_att[tid] = acc * 2.0f;   // /TEMP, TEMP=0.5
  }
  __syncthreads();
  // ---- tau, softmax, top-3 (single thread; 32 values) ----
  if (tid == 0) {
    float tau = 0.f;
    for (int r = 0; r < 64; ++r) tau += s_s[r];
    tau = tau * (1.0f / 64.0f) * 0.5f + 0.5f;
    float mx = s_att[0];
    for (int m = 1; m < 32; ++m) mx = fmaxf(mx, s_att[m]);
    float pr[32]; float sum = 0.f;
    #pragma unroll
    for (int m = 0; m < 32; ++m) { pr[m] = expf(s_att[m] - mx); sum += pr[m]; }
    float inv = 1.0f / sum;
    int i0 = -1, i1 = -1, i2 = -1; float v0 = -1.f, v1 = -1.f, v2 = -1.f;
    #pragma unroll
    for (int m = 0; m < 32; ++m) {
      float v = pr[m];
      if (v > v0)      { v2 = v1; i2 = i1; v1 = v0; i1 = i0; v0 = v; i0 = m; }
      else if (v > v1) { v2 = v1; i2 = i1; v1 = v; i1 = m; }
      else if (v > v2) { v2 = v; i2 = m; }
    }
    s_red[0] = tau; s_red[1] = v0 * inv; s_red[2] = v1 * inv; s_red[3] = v2 * inv;
    s_idx[0] = i0; s_idx[1] = i1; s_idx[2] = i2;
  }
  __syncthreads();
  // ---- q2 = tau*q1 + (1-tau)*old_q (if trigger) ----
  {
    float q1 = s_q1[tid];
    float q2;
    if (trigger[0] == 1) {
      float tau = s_red[0];
      float oq = W[tid * 32 + s_idx[0]] * s_red[1]
               + W[tid * 32 + s_idx[1]] * s_red[2]
               + W[tid * 32 + s_idx[2]] * s_red[3];
      q2 = tau * q1 + (1.0f - tau) * oq;
    } else {
      q2 = q1;
    }
    s_q2[tid] = q2;
  }
  __syncthreads();
  // ---- scw[k][o][i] = conv_w[o][i][k] * wq[o][k] * fq[o]  (bf16) ----
  for (int e = tid; e < 12288; e += 320) {
    int k = e >> 12, rem = e & 4095;
    int o = rem >> 6, i = rem & 63;
    float val = conv_w[(o * 64 + i) * 3 + k] * s_q2[o * 3 + k] * s_q2[256 + o];
    scw[e] = f2bf(val);
  }
  // ---- sbias[o] = fq*conv_b*bq ----
  if (tid < 64) sbias[tid] = s_q2[256 + tid] * conv_b[tid] * s_q2[192 + tid];
}

// ---------------- kernel 2: conv as bf16 MFMA GEMM ----------------
// D[t][o] = sum_i x[t+k-1][i] * w_k[o][i].  A = x (M=t), B = weights (N=o).
// C/D: row=t=quad*4+reg, col=o=lane&15 -> float4 output stores.
// One tile (128 t x 64 o) per block, grid (64,64) = 4096 blocks: cross-block TLP
// does the pipelining (explicit in-block pipelining at 2 blocks/CU was a 91us
// regression -- Common-mistake #5).
// Staging: thread loads 8 float4 from 8 CONSECUTIVE i-rows at one t-quad
// (coalesced: per instr a wave covers 2 rows x 512 B), then writes 4x
// ds_write_b128 (8 consecutive i at one t). With TP=72 each write instr hits 4
// disjoint 4-bank slots (~2x b128 floor) -- replaces the 16-way-conflicted
// scalar b16 writes (17.3M conflict cycles/dispatch).
__global__ __launch_bounds__(256, 4) void k_conv(const float* __restrict__ x,
    const unsigned short* __restrict__ scw, const float* __restrict__ sbias,
    float* __restrict__ out) {
  __shared__ __align__(16) unsigned short xs[130 * TP];   // [tr][i], tr = t_local + 1
  __shared__ float sb[64];
  const int tid = threadIdx.x;
  const int b = blockIdx.y;
  const int t0 = blockIdx.x * TT;

  const int lane = tid & 63;
  const int wv   = tid >> 6;
  const int quad = lane >> 4;
  const int l15  = lane & 15;
  const int wt   = (wv & 1) * 64;   // wave t-offset within tile
  const int wo   = (wv >> 1) * 32;  // wave o-offset

  if (tid < 64) sb[tid] = sbias[tid];

  // B fragments (weights): B[c = quad*8+j][n = l15], n->o, c->i. 12 x 16B loads (L2-hot).
  bf16x8 wfr[3][2][2];
  #pragma unroll
  for (int k = 0; k < 3; ++k)
    #pragma unroll
    for (int ii = 0; ii < 2; ++ii)
      #pragma unroll
      for (int n = 0; n < 2; ++n)
        wfr[k][ii][n] = *(const bf16x8*)(scw + k * 4096 + (wo + n * 16 + l15) * 64 + ii * 32 + quad * 8);

  // ---- stage x[b, :, t0-1 .. t0+128] transposed into xs[t][i] ----
  const int q   = tid & 31;    // t-quad: t = q*4 + e
  const int oct = tid >> 5;    // i-octet: i = oct*8 + rr
  const float* xb = x + (size_t)b * (64 * 8192);
  const float* xp = xb + (size_t)(oct * 8) * 8192 + t0 + q * 4;
  f32x4 arr[8];
  #pragma unroll
  for (int rr = 0; rr < 8; ++rr)
    arr[rr] = *(const f32x4*)(xp + (size_t)rr * 8192);

  // Halo loads (t0-1, t0+128) issued in the same vmcnt window.
  float hv = 0.0f;
  if (tid < 128) {
    const int side = tid >> 6;
    const int i    = tid & 63;
    const int tg   = side ? (t0 + TT) : (t0 - 1);
    if (tg >= 0 && tg < 8192) hv = xb[(size_t)i * 8192 + tg];
  }

  // Transpose in-register: one b128 write per t element (8 consecutive i).
  #pragma unroll
  for (int e = 0; e < 4; ++e) {
    u16x8 v;
    #pragma unroll
    for (int rr = 0; rr < 8; ++rr) v[rr] = f2bf(arr[rr][e]);
    *(u16x8*)(xs + (q * 4 + e + 1) * TP + oct * 8) = v;
  }
  if (tid < 128) {
    const int side = tid >> 6;
    const int i    = tid & 63;
    xs[(side ? 129 : 0) * TP + i] = f2bf(hv);
  }

  __syncthreads();

  f32x4 acc[4][2];   // [m (t-frag)][n (o-frag)]
  #pragma unroll
  for (int m = 0; m < 4; ++m)
    #pragma unroll
    for (int n = 0; n < 2; ++n)
      acc[m][n] = (f32x4){0.f, 0.f, 0.f, 0.f};

  // A fragment (x): A[m = l15][c = quad*8+j]: row tr = wt + m*16 + l15 + k,
  // cols i = ii*32 + quad*8 .. +7 -> one ds_read_b128, compile-time offsets.
  const char* xsb = (const char*)xs + (wt + l15) * (TP * 2) + quad * 16;
  #pragma unroll
  for (int k = 0; k < 3; ++k) {
    #pragma unroll
    for (int ii = 0; ii < 2; ++ii) {
      #pragma unroll
      for (int m = 0; m < 4; ++m) {
        const bf16x8 afr = *(const bf16x8*)(xsb + (m * 16 + k) * (TP * 2) + ii * 64);
        acc[m][0] = __builtin_amdgcn_mfma_f32_16x16x32_bf16(afr, wfr[k][ii][0], acc[m][0], 0, 0, 0);
        acc[m][1] = __builtin_amdgcn_mfma_f32_16x16x32_bf16(afr, wfr[k][ii][1], acc[m][1], 0, 0, 0);
      }
    }
  }

  // epilogue: lane holds t = quad*4 + {0..3} at o = wo + n*16 + l15 -> float4 store.
  #pragma unroll
  for (int m = 0; m < 4; ++m) {
    #pragma unroll
    for (int n = 0; n < 2; ++n) {
      const int o = wo + n * 16 + l15;
      const float bias = sb[o];
      f32x4 v = acc[m][n];
      v[0] += bias; v[1] += bias; v[2] += bias; v[3] += bias;
      float* op = out + ((size_t)(b * 64 + o)) * 8192 + t0 + wt + m * 16 + quad * 4;
      *(f32x4*)op = v;
    }
  }
}

extern "C" void kernel_launch(void* const* d_in, const int* in_sizes, int n_in,
                              void* d_out, int out_size, void* d_ws, size_t ws_size,
                              hipStream_t stream) {
  const float* x      = (const float*)d_in[0];
  const float* grads  = (const float*)d_in[1];
  const float* q_ema  = (const float*)d_in[2];
  const float* W      = (const float*)d_in[3];
  const float* conv_w = (const float*)d_in[4];
  const float* conv_b = (const float*)d_in[5];
  const float* ctrl_w = (const float*)d_in[6];
  const float* ctrl_b = (const float*)d_in[7];
  const float* cw_w   = (const float*)d_in[8];
  const float* cw_b   = (const float*)d_in[9];
  const float* cb_w   = (const float*)d_in[10];
  const float* cb_b   = (const float*)d_in[11];
  const float* cf_w   = (const float*)d_in[12];
  const float* cf_b   = (const float*)d_in[13];
  const float* tau_w1 = (const float*)d_in[14];
  const float* tau_b1 = (const float*)d_in[15];
  const float* tau_w2 = (const float*)d_in[16];
  const float* tau_b2 = (const float*)d_in[17];
  const int*   trigger = (const int*)d_in[18];
  float* out = (float*)d_out;

  // workspace layout: rep fp32[4096] @0 | scw bf16[12288] @16384 | sbias fp32[64] @40960
  float*          ws_rep   = (float*)d_ws;
  unsigned short* ws_scw   = (unsigned short*)((char*)d_ws + 16384);
  float*          ws_sbias = (float*)((char*)d_ws + 16384 + 24576);

  k_rep<<<16, 256, 0, stream>>>(grads, ctrl_w, ctrl_b, ws_rep);
  k_qpipe<<<1, 320, 0, stream>>>(ws_rep, q_ema, W, conv_w, conv_b, cw_w, cw_b, cb_w, cb_b,
                                 cf_w, cf_b, tau_w1, tau_b1, tau_w2, tau_b2, trigger,
                                 ws_scw, ws_sbias);
  k_conv<<<dim3(64, 64), 256, 0, stream>>>(x, ws_scw, ws_sbias, out);
}